// Round 9
// baseline (426.544 us; speedup 1.0000x reference)
//
#include <hip/hip_runtime.h>
#include <stdint.h>

#define NR 8192
#define DE 1024
#define DC 512
#define BIGF 9999999.0f
#define MARG 0.3f
#define NEGI -3.0e38f
#define POSI 3.0e38f

typedef __attribute__((ext_vector_type(8))) short bf16x8;
typedef __attribute__((ext_vector_type(4))) float f32x4;

typedef __attribute__((address_space(3))) unsigned int lds_u32;
typedef const __attribute__((address_space(1))) unsigned int glb_u32;

static __device__ __forceinline__ void ld_g2l16(const void* g, void* l) {
    __builtin_amdgcn_global_load_lds((glb_u32*)g, (lds_u32*)l, 16, 0, 0);
}

static __device__ __forceinline__ unsigned short f2bf(float x) {
    unsigned u = __float_as_uint(x);
    unsigned r = u + 0x7FFFu + ((u >> 16) & 1u);
    return (unsigned short)(r >> 16);
}

static __device__ __forceinline__ float b2f(short u) {
    return __uint_as_float(((unsigned)(unsigned short)u) << 16);
}

// ---------------- K1: emb -> bf16, sq[i] = ||emb_i||^2; init mnA; zero out ----------------
__global__ __launch_bounds__(256) void k_prep_emb(const float* __restrict__ emb,
                                                  short* __restrict__ embb,
                                                  float* __restrict__ sq,
                                                  unsigned* __restrict__ mnA,
                                                  float* __restrict__ out) {
    int row = blockIdx.x, tid = threadIdx.x;
    float4 v = ((const float4*)(emb + (size_t)row * DE))[tid];
    float s = v.x * v.x + v.y * v.y + v.z * v.z + v.w * v.w;
    ushort4 b;
    b.x = f2bf(v.x); b.y = f2bf(v.y); b.z = f2bf(v.z); b.w = f2bf(v.w);
    *(ushort4*)&embb[(size_t)row * DE + tid * 4] = b;
    for (int m = 1; m < 64; m <<= 1) s += __shfl_xor(s, m);
    __shared__ float red[4];
    if ((tid & 63) == 0) red[tid >> 6] = s;
    __syncthreads();
    if (tid == 0) {
        sq[row] = red[0] + red[1] + red[2] + red[3];
        mnA[row] = 0xFFFFFFFFu;                 // +inf bits for positive-float min
    }
    if (row == 0 && tid < 2) out[tid] = 0.f;    // k_pos accumulates loss/prec atomically
}

// ---------------- K2: histogram + scan + class member lists (single block) ----------------
__global__ __launch_bounds__(512) void k_hist(const int* __restrict__ label,
                                              int* __restrict__ cnt,
                                              int* __restrict__ cOff,
                                              int* __restrict__ list) {
    __shared__ int h[512], s[512], base[512];
    int t = threadIdx.x;
    h[t] = 0;
    __syncthreads();
    for (int i = t; i < NR; i += 512) atomicAdd(&h[label[i]], 1);
    __syncthreads();
    int c = h[t];
    s[t] = c;
    __syncthreads();
    for (int d = 1; d < 512; d <<= 1) {
        int v = (t >= d) ? s[t - d] : 0;
        __syncthreads();
        s[t] += v;
        __syncthreads();
    }
    cnt[t] = c;
    cOff[t] = s[t] - c;
    base[t] = s[t] - c;
    __syncthreads();
    for (int i = t; i < NR; i += 512) {
        int l = label[i];
        int p = atomicAdd(&base[l], 1);
        list[p] = i;       // order within class irrelevant: k_pos tie-breaks by index
    }
}

// ---------------- K3: per-tile symmetric GEMM + min-negative row/col atomics ----------------
// 2080 blocks, one 128x128 tile each: t -> (p,q), 0<=p<=q<64, t = q(q+1)/2 + p.
// 64x64 wave tiles (2x2 grid): 8 ds_read_b128 per wave-ks for 16 MFMAs (vs 10 at 32x128).
// Negative side needs min value only; positives recomputed exactly in k_pos.
__global__ __launch_bounds__(256, 4) void k_main(const short* __restrict__ embb,
                                                 const float* __restrict__ sq,
                                                 const int* __restrict__ label,
                                                 unsigned* __restrict__ mnA) {
    const int t = blockIdx.x;
    int qq = (int)((sqrtf(8.0f * (float)t + 1.0f) - 1.0f) * 0.5f);
    while ((qq + 1) * (qq + 2) / 2 <= t) ++qq;
    while (qq * (qq + 1) / 2 > t) --qq;
    const int pq = t - qq * (qq + 1) / 2;
    const int i0 = pq * 128, j0 = qq * 128;   // rows panel p, cols panel q (p <= q)

    __shared__ __align__(16) short As[128 * 32];
    __shared__ __align__(16) short Bs[128 * 32];

    const int tid = threadIdx.x;
    const int lane = tid & 63;
    const int w = tid >> 6;
    const int wm = w >> 1, wn = w & 1;
    const int q = lane >> 4, l15 = lane & 15;

    // staging source swizzle (conflict-free, SQ_LDS_BANK_CONFLICT=0 since R4)
    const int srow = tid >> 2;
    const int g = (tid & 3) ^ ((tid >> 3) & 3);
    const short* gA = embb + (size_t)(i0 + srow) * DE + g * 8;
    const short* gB = embb + (size_t)(j0 + srow) * DE + g * 8;
    const int pxor = q ^ ((l15 >> 1) & 3);

    auto stage = [&](int koff) {
        ld_g2l16(gA + koff, &As[(size_t)tid * 8]);
        ld_g2l16(gA + (size_t)64 * DE + koff, &As[(size_t)(tid + 256) * 8]);
        ld_g2l16(gB + koff, &Bs[(size_t)tid * 8]);
        ld_g2l16(gB + (size_t)64 * DE + koff, &Bs[(size_t)(tid + 256) * 8]);
    };

    f32x4 acc[4][4];
#pragma unroll
    for (int mi = 0; mi < 4; ++mi)
#pragma unroll
        for (int ni = 0; ni < 4; ++ni) acc[mi][ni] = (f32x4){0.f, 0.f, 0.f, 0.f};

    stage(0);
    for (int ks = 0; ks < 32; ++ks) {
        __syncthreads();              // staging visible
        bf16x8 af[4], bfr[4];
#pragma unroll
        for (int mi = 0; mi < 4; ++mi)
            af[mi] = *(const bf16x8*)&As[(wm * 64 + mi * 16 + l15) * 32 + pxor * 8];
#pragma unroll
        for (int ni = 0; ni < 4; ++ni)
            bfr[ni] = *(const bf16x8*)&Bs[(wn * 64 + ni * 16 + l15) * 32 + pxor * 8];
#pragma unroll
        for (int mi = 0; mi < 4; ++mi)
#pragma unroll
            for (int ni = 0; ni < 4; ++ni)
                acc[mi][ni] = __builtin_amdgcn_mfma_f32_16x16x32_bf16(af[mi], bfr[ni], acc[mi][ni], 0, 0, 0);
        __syncthreads();              // reads done before next staging
        if (ks < 31) stage((ks + 1) * 32);
    }

    // ---- epilogue: row mins + col mins, straight to atomics ----
    // Diagonal tile (p==q) double-covers pairs from both sides: harmless for min.
    float sqj[4]; int lbj[4];
#pragma unroll
    for (int ni = 0; ni < 4; ++ni) {
        int cg = j0 + wn * 64 + ni * 16 + l15;
        sqj[ni] = sq[cg]; lbj[ni] = label[cg];
    }
    float cmn[4] = {POSI, POSI, POSI, POSI};
#pragma unroll
    for (int mi = 0; mi < 4; ++mi) {
#pragma unroll
        for (int r = 0; r < 4; ++r) {
            const int rowg = i0 + wm * 64 + mi * 16 + q * 4 + r;
            const float si = sq[rowg];
            const int li = label[rowg];
            float rm = POSI;
#pragma unroll
            for (int ni = 0; ni < 4; ++ni) {
                float d2 = fmaf(-2.0f, acc[mi][ni][r], si + sqj[ni]);
                d2 = fmaxf(d2, 1e-12f);
                float dn = (li == lbj[ni]) ? POSI : d2;
                rm = fminf(rm, dn);
                cmn[ni] = fminf(cmn[ni], dn);
            }
            // combine the 16 cols (l15) for this row; rows differ only across q
            for (int s = 1; s <= 8; s <<= 1) rm = fminf(rm, __shfl_xor(rm, s));
            if (l15 == 0) atomicMin(&mnA[rowg], __float_as_uint(rm));
        }
    }
#pragma unroll
    for (int ni = 0; ni < 4; ++ni) {
        float c = cmn[ni];
        c = fminf(c, __shfl_xor(c, 16));
        c = fminf(c, __shfl_xor(c, 32));
        if (q == 0) atomicMin(&mnA[j0 + wn * 64 + ni * 16 + l15], __float_as_uint(c));
    }
}

// ---------------- K4: exact per-row positives + alphas + fused loss accumulation ----------------
// one wave per row; ~16 classmates, exact top-2 with jax tie-break (lower index).
__global__ __launch_bounds__(256) void k_pos(const short* __restrict__ embb,
                                             const float* __restrict__ sq,
                                             const float* __restrict__ clot,
                                             const int* __restrict__ label,
                                             const int* __restrict__ cnt,
                                             const int* __restrict__ clsOff,
                                             const int* __restrict__ clsList,
                                             const unsigned* __restrict__ mnA,
                                             float* __restrict__ out) {
    int wid = threadIdx.x >> 6, lane = threadIdx.x & 63;
    int row = blockIdx.x * 4 + wid;
    int lb = label[row];
    int cc = cnt[lb], off = clsOff[lb];
    float sqiv = sq[row];

    const bf16x8* rp = (const bf16x8*)(embb + (size_t)row * DE + lane * 16);
    bf16x8 ra = rp[0], rb = rp[1];
    float rf[16];
#pragma unroll
    for (int u = 0; u < 8; ++u) { rf[u] = b2f(ra[u]); rf[8 + u] = b2f(rb[u]); }

    float v1 = NEGI, v2 = NEGI;
    int i1 = 0, i2 = 0;
    for (int m = 0; m < cc; ++m) {
        int j = clsList[off + m];
        float d2;
        if (j == row) {
            d2 = 1e-12f;                       // d(i,i) after clip: ranks last
        } else {
            const bf16x8* jp = (const bf16x8*)(embb + (size_t)j * DE + lane * 16);
            bf16x8 ja = jp[0], jb = jp[1];
            float s = 0.f;
#pragma unroll
            for (int u = 0; u < 8; ++u) s = fmaf(rf[u], b2f(ja[u]), s);
#pragma unroll
            for (int u = 0; u < 8; ++u) s = fmaf(rf[8 + u], b2f(jb[u]), s);
            for (int mm = 1; mm < 64; mm <<= 1) s += __shfl_xor(s, mm);
            d2 = fmaxf(fmaf(-2.0f, s, sqiv + sq[j]), 1e-12f);
        }
        bool t1 = (d2 > v1) || (d2 == v1 && j < i1);
        bool t2 = (d2 > v2) || (d2 == v2 && j < i2);
        v2 = t1 ? v1 : (t2 ? d2 : v2);
        i2 = t1 ? i1 : (t2 ? j : i2);
        v1 = t1 ? d2 : v1;
        i1 = t1 ? j : i1;
    }

    float dap1 = sqrtf(v1);
    int j1 = i1;
    float dap2; int j2;
    if (cc >= 2) {
        dap2 = sqrtf(v2);
        j2 = i2;
    } else {
        // singleton class (expected never): ref falls back to max-dist negative - BIG
        float kv = NEGI; int ki = 0;
        const short* rrow = embb + (size_t)row * DE;
        for (int c = lane; c < NR; c += 64) {
            if (label[c] == lb) continue;
            const short* crow = embb + (size_t)c * DE;
            float s = 0.f;
            for (int u = 0; u < DE; ++u) s = fmaf(b2f(rrow[u]), b2f(crow[u]), s);
            float d2c = fmaxf(fmaf(-2.0f, s, sqiv + sq[c]), 1e-12f);
            bool tk = (d2c > kv) || (d2c == kv && c < ki);
            kv = tk ? d2c : kv; ki = tk ? c : ki;
        }
        for (int mm = 1; mm < 64; mm <<= 1) {
            float ov = __shfl_xor(kv, mm); int oi = __shfl_xor(ki, mm);
            bool tk = (ov > kv) || (ov == kv && oi < ki);
            kv = tk ? ov : kv; ki = tk ? oi : ki;
        }
        dap2 = sqrtf(kv) - BIGF;
        j2 = ki;
    }

    // alpha dots + norms over clot
    const float4* c4 = (const float4*)clot;
    float s1 = 0.f, s2 = 0.f, n0 = 0.f, n1 = 0.f, n2 = 0.f;
    for (int u = lane; u < DC / 4; u += 64) {
        float4 a = c4[(size_t)row * (DC / 4) + u];
        float4 b1 = c4[(size_t)j1 * (DC / 4) + u];
        float4 b2 = c4[(size_t)j2 * (DC / 4) + u];
        s1 += a.x * b1.x + a.y * b1.y + a.z * b1.z + a.w * b1.w;
        s2 += a.x * b2.x + a.y * b2.y + a.z * b2.z + a.w * b2.w;
        n0 += a.x * a.x + a.y * a.y + a.z * a.z + a.w * a.w;
        n1 += b1.x * b1.x + b1.y * b1.y + b1.z * b1.z + b1.w * b1.w;
        n2 += b2.x * b2.x + b2.y * b2.y + b2.z * b2.z + b2.w * b2.w;
    }
    for (int mm = 1; mm < 64; mm <<= 1) {
        s1 += __shfl_xor(s1, mm); s2 += __shfl_xor(s2, mm);
        n0 += __shfl_xor(n0, mm); n1 += __shfl_xor(n1, mm); n2 += __shfl_xor(n2, mm);
    }
    if (lane == 0) {
        float al1 = s1 / (sqrtf(n0) * sqrtf(n1));
        float al2 = s2 / (sqrtf(n0) * sqrtf(n2));
        float dan = sqrtf(__uint_as_float(mnA[row]));
        float y = (al1 < al2) ? -1.f : 1.f;
        float ym = (al1 == al2) ? 0.f : 1.f;
        float x1 = dap2 * ym;
        float x2 = dap1 * ym + MARG * (al1 - al2 - y);
        float l11 = fmaxf(0.f, -y * (x1 - x2) + MARG);
        float ap1m = dap1 + MARG * (al1 - 1.f);
        float l13 = fmaxf(0.f, -(dan - ap1m) + MARG);
        atomicAdd(&out[0], (0.1f * l11 + l13) * (1.0f / (float)NR));
        atomicAdd(&out[1], ((dan > ap1m) ? 1.f : 0.f) * (1.0f / (float)NR));
    }
}

extern "C" void kernel_launch(void* const* d_in, const int* in_sizes, int n_in,
                              void* d_out, int out_size, void* d_ws, size_t ws_size,
                              hipStream_t stream) {
    const float* emb = (const float*)d_in[0];
    const int* label = (const int*)d_in[1];
    const float* clot = (const float*)d_in[2];
    float* out = (float*)d_out;

    char* ws = (char*)d_ws;
    size_t off = 0;
    auto alloc = [&](size_t bytes) -> char* {
        char* p = ws + off;
        off = (off + bytes + 255) & ~(size_t)255;
        return p;
    };
    short*    embb = (short*)alloc((size_t)NR * DE * 2);
    float*    sq   = (float*)alloc(NR * 4);
    int*      cnt  = (int*)alloc(512 * 4);
    int*      cOff = (int*)alloc(512 * 4);
    int*      list = (int*)alloc(NR * 4);
    unsigned* mnA  = (unsigned*)alloc((size_t)NR * 4);

    k_prep_emb<<<dim3(NR), dim3(256), 0, stream>>>(emb, embb, sq, mnA, out);
    k_hist<<<dim3(1), dim3(512), 0, stream>>>(label, cnt, cOff, list);
    k_main<<<dim3(2080), dim3(256), 0, stream>>>(embb, sq, label, mnA);
    k_pos<<<dim3(NR / 4), dim3(256), 0, stream>>>(embb, sq, clot, label, cnt, cOff, list,
                                                  mnA, out);
}

// Round 10
// 281.838 us; speedup vs baseline: 1.5134x; 1.5134x over previous
//
#include <hip/hip_runtime.h>
#include <stdint.h>

#define NR 8192
#define DE 1024
#define DC 512
#define BIGF 9999999.0f
#define MARG 0.3f
#define NEGI -3.0e38f
#define POSI 3.0e38f

typedef __attribute__((ext_vector_type(8))) short bf16x8;
typedef __attribute__((ext_vector_type(4))) float f32x4;

typedef __attribute__((address_space(3))) unsigned int lds_u32;
typedef const __attribute__((address_space(1))) unsigned int glb_u32;

static __device__ __forceinline__ void ld_g2l16(const void* g, void* l) {
    __builtin_amdgcn_global_load_lds((glb_u32*)g, (lds_u32*)l, 16, 0, 0);
}

static __device__ __forceinline__ unsigned short f2bf(float x) {
    unsigned u = __float_as_uint(x);
    unsigned r = u + 0x7FFFu + ((u >> 16) & 1u);
    return (unsigned short)(r >> 16);
}

static __device__ __forceinline__ float b2f(short u) {
    return __uint_as_float(((unsigned)(unsigned short)u) << 16);
}

// ---------------- K1: emb -> bf16, sq[i] = ||emb_i||^2; init mnA; zero out ----------------
__global__ __launch_bounds__(256) void k_prep_emb(const float* __restrict__ emb,
                                                  short* __restrict__ embb,
                                                  float* __restrict__ sq,
                                                  unsigned* __restrict__ mnA,
                                                  float* __restrict__ out) {
    int row = blockIdx.x, tid = threadIdx.x;
    float4 v = ((const float4*)(emb + (size_t)row * DE))[tid];
    float s = v.x * v.x + v.y * v.y + v.z * v.z + v.w * v.w;
    ushort4 b;
    b.x = f2bf(v.x); b.y = f2bf(v.y); b.z = f2bf(v.z); b.w = f2bf(v.w);
    *(ushort4*)&embb[(size_t)row * DE + tid * 4] = b;
    for (int m = 1; m < 64; m <<= 1) s += __shfl_xor(s, m);
    __shared__ float red[4];
    if ((tid & 63) == 0) red[tid >> 6] = s;
    __syncthreads();
    if (tid == 0) {
        sq[row] = red[0] + red[1] + red[2] + red[3];
        mnA[row] = 0xFFFFFFFFu;                 // +inf bits for positive-float min
    }
    if (row == 0 && tid < 2) out[tid] = 0.f;    // k_pos accumulates loss/prec atomically
}

// ---------------- K2: histogram + scan + class member lists (single block) ----------------
__global__ __launch_bounds__(512) void k_hist(const int* __restrict__ label,
                                              int* __restrict__ cnt,
                                              int* __restrict__ cOff,
                                              int* __restrict__ list) {
    __shared__ int h[512], s[512], base[512];
    int t = threadIdx.x;
    h[t] = 0;
    __syncthreads();
    for (int i = t; i < NR; i += 512) atomicAdd(&h[label[i]], 1);
    __syncthreads();
    int c = h[t];
    s[t] = c;
    __syncthreads();
    for (int d = 1; d < 512; d <<= 1) {
        int v = (t >= d) ? s[t - d] : 0;
        __syncthreads();
        s[t] += v;
        __syncthreads();
    }
    cnt[t] = c;
    cOff[t] = s[t] - c;
    base[t] = s[t] - c;
    __syncthreads();
    for (int i = t; i < NR; i += 512) {
        int l = label[i];
        int p = atomicAdd(&base[l], 1);
        list[p] = i;       // order within class irrelevant: k_pos tie-breaks by index
    }
}

// ---------------- K3: per-tile symmetric GEMM + min-negative row/col atomics ----------------
// 2080 blocks, one 128x128 tile each: t -> (p,q), 0<=p<=q<64, t = q(q+1)/2 + p.
// 64x64 wave tiles (2x2 grid). Negative side needs min value only; positives exact in k_pos.
__global__ __launch_bounds__(256, 4) void k_main(const short* __restrict__ embb,
                                                 const float* __restrict__ sq,
                                                 const int* __restrict__ label,
                                                 unsigned* __restrict__ mnA) {
    const int t = blockIdx.x;
    int qq = (int)((sqrtf(8.0f * (float)t + 1.0f) - 1.0f) * 0.5f);
    while ((qq + 1) * (qq + 2) / 2 <= t) ++qq;
    while (qq * (qq + 1) / 2 > t) --qq;
    const int pq = t - qq * (qq + 1) / 2;
    const int i0 = pq * 128, j0 = qq * 128;   // rows panel p, cols panel q (p <= q)

    __shared__ __align__(16) short As[128 * 32];
    __shared__ __align__(16) short Bs[128 * 32];

    const int tid = threadIdx.x;
    const int lane = tid & 63;
    const int w = tid >> 6;
    const int wm = w >> 1, wn = w & 1;
    const int q = lane >> 4, l15 = lane & 15;

    // staging source swizzle (conflict-free, SQ_LDS_BANK_CONFLICT=0 since R4)
    const int srow = tid >> 2;
    const int g = (tid & 3) ^ ((tid >> 3) & 3);
    const short* gA = embb + (size_t)(i0 + srow) * DE + g * 8;
    const short* gB = embb + (size_t)(j0 + srow) * DE + g * 8;
    const int pxor = q ^ ((l15 >> 1) & 3);

    auto stage = [&](int koff) {
        ld_g2l16(gA + koff, &As[(size_t)tid * 8]);
        ld_g2l16(gA + (size_t)64 * DE + koff, &As[(size_t)(tid + 256) * 8]);
        ld_g2l16(gB + koff, &Bs[(size_t)tid * 8]);
        ld_g2l16(gB + (size_t)64 * DE + koff, &Bs[(size_t)(tid + 256) * 8]);
    };

    f32x4 acc[4][4];
#pragma unroll
    for (int mi = 0; mi < 4; ++mi)
#pragma unroll
        for (int ni = 0; ni < 4; ++ni) acc[mi][ni] = (f32x4){0.f, 0.f, 0.f, 0.f};

    stage(0);
    for (int ks = 0; ks < 32; ++ks) {
        __syncthreads();              // staging visible
        bf16x8 af[4], bfr[4];
#pragma unroll
        for (int mi = 0; mi < 4; ++mi)
            af[mi] = *(const bf16x8*)&As[(wm * 64 + mi * 16 + l15) * 32 + pxor * 8];
#pragma unroll
        for (int ni = 0; ni < 4; ++ni)
            bfr[ni] = *(const bf16x8*)&Bs[(wn * 64 + ni * 16 + l15) * 32 + pxor * 8];
#pragma unroll
        for (int mi = 0; mi < 4; ++mi)
#pragma unroll
            for (int ni = 0; ni < 4; ++ni)
                acc[mi][ni] = __builtin_amdgcn_mfma_f32_16x16x32_bf16(af[mi], bfr[ni], acc[mi][ni], 0, 0, 0);
        __syncthreads();              // reads done before next staging
        if (ks < 31) stage((ks + 1) * 32);
    }

    // ---- epilogue: row mins + col mins, straight to atomics ----
    // Diagonal tile (p==q) double-covers pairs from both sides: harmless for min.
    float sqj[4]; int lbj[4];
#pragma unroll
    for (int ni = 0; ni < 4; ++ni) {
        int cg = j0 + wn * 64 + ni * 16 + l15;
        sqj[ni] = sq[cg]; lbj[ni] = label[cg];
    }
    float cmn[4] = {POSI, POSI, POSI, POSI};
#pragma unroll
    for (int mi = 0; mi < 4; ++mi) {
#pragma unroll
        for (int r = 0; r < 4; ++r) {
            const int rowg = i0 + wm * 64 + mi * 16 + q * 4 + r;
            const float si = sq[rowg];
            const int li = label[rowg];
            float rm = POSI;
#pragma unroll
            for (int ni = 0; ni < 4; ++ni) {
                float d2 = fmaf(-2.0f, acc[mi][ni][r], si + sqj[ni]);
                d2 = fmaxf(d2, 1e-12f);
                float dn = (li == lbj[ni]) ? POSI : d2;
                rm = fminf(rm, dn);
                cmn[ni] = fminf(cmn[ni], dn);
            }
            for (int s = 1; s <= 8; s <<= 1) rm = fminf(rm, __shfl_xor(rm, s));
            if (l15 == 0) atomicMin(&mnA[rowg], __float_as_uint(rm));
        }
    }
#pragma unroll
    for (int ni = 0; ni < 4; ++ni) {
        float c = cmn[ni];
        c = fminf(c, __shfl_xor(c, 16));
        c = fminf(c, __shfl_xor(c, 32));
        if (q == 0) atomicMin(&mnA[j0 + wn * 64 + ni * 16 + l15], __float_as_uint(c));
    }
}

// ---------------- K4: exact per-row positives + alphas + loss (block-reduced) ----------------
// one wave per row; classmates processed in chunks of 8 (independent loads/butterflies
// for ILP — R9's serial chain was latency-bound). Per-BLOCK loss reduction via LDS,
// one atomicAdd pair per block (R9's per-row same-address atomics serialized: 227 us).
__global__ __launch_bounds__(256) void k_pos(const short* __restrict__ embb,
                                             const float* __restrict__ sq,
                                             const float* __restrict__ clot,
                                             const int* __restrict__ label,
                                             const int* __restrict__ cnt,
                                             const int* __restrict__ clsOff,
                                             const int* __restrict__ clsList,
                                             const unsigned* __restrict__ mnA,
                                             float* __restrict__ out) {
    int wid = threadIdx.x >> 6, lane = threadIdx.x & 63;
    int row = blockIdx.x * 4 + wid;
    int lb = label[row];
    int cc = cnt[lb], off = clsOff[lb];
    float sqiv = sq[row];

    const bf16x8* rp = (const bf16x8*)(embb + (size_t)row * DE + lane * 16);
    bf16x8 ra = rp[0], rb = rp[1];
    float rf[16];
#pragma unroll
    for (int u = 0; u < 8; ++u) { rf[u] = b2f(ra[u]); rf[8 + u] = b2f(rb[u]); }

    float v1 = NEGI, v2 = NEGI;
    int i1 = 0, i2 = 0;
    for (int m0 = 0; m0 < cc; m0 += 8) {
        float sv[8]; int jv[8];
#pragma unroll
        for (int u = 0; u < 8; ++u) {
            int mm = m0 + u;
            int j = (mm < cc) ? clsList[off + mm] : row;   // pad with self, guarded below
            jv[u] = j;
            const bf16x8* jp = (const bf16x8*)(embb + (size_t)j * DE + lane * 16);
            bf16x8 ja = jp[0], jb = jp[1];
            float s = 0.f;
#pragma unroll
            for (int u2 = 0; u2 < 8; ++u2) s = fmaf(rf[u2], b2f(ja[u2]), s);
#pragma unroll
            for (int u2 = 0; u2 < 8; ++u2) s = fmaf(rf[8 + u2], b2f(jb[u2]), s);
            sv[u] = s;
        }
#pragma unroll
        for (int u = 0; u < 8; ++u)
            for (int mm = 1; mm < 64; mm <<= 1) sv[u] += __shfl_xor(sv[u], mm);
#pragma unroll
        for (int u = 0; u < 8; ++u) {
            int mm = m0 + u;
            if (mm < cc) {
                int j = jv[u];
                float d2 = (j == row) ? 1e-12f
                                      : fmaxf(fmaf(-2.0f, sv[u], sqiv + sq[j]), 1e-12f);
                bool t1 = (d2 > v1) || (d2 == v1 && j < i1);
                bool t2 = (d2 > v2) || (d2 == v2 && j < i2);
                v2 = t1 ? v1 : (t2 ? d2 : v2);
                i2 = t1 ? i1 : (t2 ? j : i2);
                v1 = t1 ? d2 : v1;
                i1 = t1 ? j : i1;
            }
        }
    }

    float dap1 = sqrtf(v1);
    int j1 = i1;
    float dap2; int j2;
    if (cc >= 2) {
        dap2 = sqrtf(v2);
        j2 = i2;
    } else {
        // singleton class (expected never): ref falls back to max-dist negative - BIG
        float kv = NEGI; int ki = 0;
        const short* rrow = embb + (size_t)row * DE;
        for (int c = lane; c < NR; c += 64) {
            if (label[c] == lb) continue;
            const short* crow = embb + (size_t)c * DE;
            float s = 0.f;
            for (int u = 0; u < DE; ++u) s = fmaf(b2f(rrow[u]), b2f(crow[u]), s);
            float d2c = fmaxf(fmaf(-2.0f, s, sqiv + sq[c]), 1e-12f);
            bool tk = (d2c > kv) || (d2c == kv && c < ki);
            kv = tk ? d2c : kv; ki = tk ? c : ki;
        }
        for (int mm = 1; mm < 64; mm <<= 1) {
            float ov = __shfl_xor(kv, mm); int oi = __shfl_xor(ki, mm);
            bool tk = (ov > kv) || (ov == kv && oi < ki);
            kv = tk ? ov : kv; ki = tk ? oi : ki;
        }
        dap2 = sqrtf(kv) - BIGF;
        j2 = ki;
    }

    // alpha dots + norms over clot
    const float4* c4 = (const float4*)clot;
    float s1 = 0.f, s2 = 0.f, n0 = 0.f, n1 = 0.f, n2 = 0.f;
    for (int u = lane; u < DC / 4; u += 64) {
        float4 a = c4[(size_t)row * (DC / 4) + u];
        float4 b1 = c4[(size_t)j1 * (DC / 4) + u];
        float4 b2 = c4[(size_t)j2 * (DC / 4) + u];
        s1 += a.x * b1.x + a.y * b1.y + a.z * b1.z + a.w * b1.w;
        s2 += a.x * b2.x + a.y * b2.y + a.z * b2.z + a.w * b2.w;
        n0 += a.x * a.x + a.y * a.y + a.z * a.z + a.w * a.w;
        n1 += b1.x * b1.x + b1.y * b1.y + b1.z * b1.z + b1.w * b1.w;
        n2 += b2.x * b2.x + b2.y * b2.y + b2.z * b2.z + b2.w * b2.w;
    }
    for (int mm = 1; mm < 64; mm <<= 1) {
        s1 += __shfl_xor(s1, mm); s2 += __shfl_xor(s2, mm);
        n0 += __shfl_xor(n0, mm); n1 += __shfl_xor(n1, mm); n2 += __shfl_xor(n2, mm);
    }

    __shared__ float sLoss[4], sPrec[4];
    if (lane == 0) {
        float al1 = s1 / (sqrtf(n0) * sqrtf(n1));
        float al2 = s2 / (sqrtf(n0) * sqrtf(n2));
        float dan = sqrtf(__uint_as_float(mnA[row]));
        float y = (al1 < al2) ? -1.f : 1.f;
        float ym = (al1 == al2) ? 0.f : 1.f;
        float x1 = dap2 * ym;
        float x2 = dap1 * ym + MARG * (al1 - al2 - y);
        float l11 = fmaxf(0.f, -y * (x1 - x2) + MARG);
        float ap1m = dap1 + MARG * (al1 - 1.f);
        float l13 = fmaxf(0.f, -(dan - ap1m) + MARG);
        sLoss[wid] = (0.1f * l11 + l13) * (1.0f / (float)NR);
        sPrec[wid] = ((dan > ap1m) ? 1.f : 0.f) * (1.0f / (float)NR);
    }
    __syncthreads();
    if (threadIdx.x == 0) {
        atomicAdd(&out[0], sLoss[0] + sLoss[1] + sLoss[2] + sLoss[3]);
        atomicAdd(&out[1], sPrec[0] + sPrec[1] + sPrec[2] + sPrec[3]);
    }
}

extern "C" void kernel_launch(void* const* d_in, const int* in_sizes, int n_in,
                              void* d_out, int out_size, void* d_ws, size_t ws_size,
                              hipStream_t stream) {
    const float* emb = (const float*)d_in[0];
    const int* label = (const int*)d_in[1];
    const float* clot = (const float*)d_in[2];
    float* out = (float*)d_out;

    char* ws = (char*)d_ws;
    size_t off = 0;
    auto alloc = [&](size_t bytes) -> char* {
        char* p = ws + off;
        off = (off + bytes + 255) & ~(size_t)255;
        return p;
    };
    short*    embb = (short*)alloc((size_t)NR * DE * 2);
    float*    sq   = (float*)alloc(NR * 4);
    int*      cnt  = (int*)alloc(512 * 4);
    int*      cOff = (int*)alloc(512 * 4);
    int*      list = (int*)alloc(NR * 4);
    unsigned* mnA  = (unsigned*)alloc((size_t)NR * 4);

    k_prep_emb<<<dim3(NR), dim3(256), 0, stream>>>(emb, embb, sq, mnA, out);
    k_hist<<<dim3(1), dim3(512), 0, stream>>>(label, cnt, cOff, list);
    k_main<<<dim3(2080), dim3(256), 0, stream>>>(embb, sq, label, mnA);
    k_pos<<<dim3(NR / 4), dim3(256), 0, stream>>>(embb, sq, clot, label, cnt, cOff, list,
                                                  mnA, out);
}

// Round 11
// 266.379 us; speedup vs baseline: 1.6013x; 1.0580x over previous
//
#include <hip/hip_runtime.h>
#include <stdint.h>

#define NR 8192
#define DE 1024
#define DC 512
#define BIGF 9999999.0f
#define MARG 0.3f
#define NEGI -3.0e38f
#define POSI 3.0e38f

typedef __attribute__((ext_vector_type(8))) short bf16x8;
typedef __attribute__((ext_vector_type(4))) float f32x4;

typedef __attribute__((address_space(3))) unsigned int lds_u32;
typedef const __attribute__((address_space(1))) unsigned int glb_u32;

static __device__ __forceinline__ void ld_g2l16(const void* g, void* l) {
    __builtin_amdgcn_global_load_lds((glb_u32*)g, (lds_u32*)l, 16, 0, 0);
}

static __device__ __forceinline__ unsigned short f2bf(float x) {
    unsigned u = __float_as_uint(x);
    unsigned r = u + 0x7FFFu + ((u >> 16) & 1u);
    return (unsigned short)(r >> 16);
}

static __device__ __forceinline__ float b2f(short u) {
    return __uint_as_float(((unsigned)(unsigned short)u) << 16);
}

// ---------------- K1: emb -> bf16, sq[i] = ||emb_i||^2; init mnA; zero out ----------------
__global__ __launch_bounds__(256) void k_prep_emb(const float* __restrict__ emb,
                                                  short* __restrict__ embb,
                                                  float* __restrict__ sq,
                                                  unsigned* __restrict__ mnA,
                                                  float* __restrict__ out) {
    int row = blockIdx.x, tid = threadIdx.x;
    float4 v = ((const float4*)(emb + (size_t)row * DE))[tid];
    float s = v.x * v.x + v.y * v.y + v.z * v.z + v.w * v.w;
    ushort4 b;
    b.x = f2bf(v.x); b.y = f2bf(v.y); b.z = f2bf(v.z); b.w = f2bf(v.w);
    *(ushort4*)&embb[(size_t)row * DE + tid * 4] = b;
    for (int m = 1; m < 64; m <<= 1) s += __shfl_xor(s, m);
    __shared__ float red[4];
    if ((tid & 63) == 0) red[tid >> 6] = s;
    __syncthreads();
    if (tid == 0) {
        sq[row] = red[0] + red[1] + red[2] + red[3];
        mnA[row] = 0xFFFFFFFFu;                 // +inf bits for positive-float min
    }
    if (row == 0 && tid < 2) out[tid] = 0.f;    // k_pos accumulates loss/prec atomically
}

// ---------------- K2: histogram + scan + class member lists (single block) ----------------
__global__ __launch_bounds__(512) void k_hist(const int* __restrict__ label,
                                              int* __restrict__ cnt,
                                              int* __restrict__ cOff,
                                              int* __restrict__ list) {
    __shared__ int h[512], s[512], base[512];
    int t = threadIdx.x;
    h[t] = 0;
    __syncthreads();
    for (int i = t; i < NR; i += 512) atomicAdd(&h[label[i]], 1);
    __syncthreads();
    int c = h[t];
    s[t] = c;
    __syncthreads();
    for (int d = 1; d < 512; d <<= 1) {
        int v = (t >= d) ? s[t - d] : 0;
        __syncthreads();
        s[t] += v;
        __syncthreads();
    }
    cnt[t] = c;
    cOff[t] = s[t] - c;
    base[t] = s[t] - c;
    __syncthreads();
    for (int i = t; i < NR; i += 512) {
        int l = label[i];
        int p = atomicAdd(&base[l], 1);
        list[p] = i;       // order within class irrelevant: k_pos tie-breaks by index
    }
}

// ---------------- K3: per-tile symmetric GEMM + min-negative row/col atomics ----------------
// 2080 blocks, one 128x128 tile each: t -> (p,q), 0<=p<=q<64, t = q(q+1)/2 + p.
// BK=64: stage 64-wide K slabs (32 KB LDS) -> 32 barriers/tile instead of 64.
// 8-chunk XOR swizzle: slot s of row r holds global chunk s^(r&7); readers use
// s = (q+4k)^(l15&7) -> 2 lanes/bank, conflict-free (R10: SQ_LDS_BANK_CONFLICT=0).
__global__ __launch_bounds__(256, 4) void k_main(const short* __restrict__ embb,
                                                 const float* __restrict__ sq,
                                                 const int* __restrict__ label,
                                                 unsigned* __restrict__ mnA) {
    const int t = blockIdx.x;
    int qq = (int)((sqrtf(8.0f * (float)t + 1.0f) - 1.0f) * 0.5f);
    while ((qq + 1) * (qq + 2) / 2 <= t) ++qq;
    while (qq * (qq + 1) / 2 > t) --qq;
    const int pq = t - qq * (qq + 1) / 2;
    const int i0 = pq * 128, j0 = qq * 128;   // rows panel p, cols panel q (p <= q)

    __shared__ __align__(16) short As[128 * 64];
    __shared__ __align__(16) short Bs[128 * 64];

    const int tid = threadIdx.x;
    const int lane = tid & 63;
    const int w = tid >> 6;
    const int wm = w >> 1, wn = w & 1;
    const int q = lane >> 4, l15 = lane & 15;

    // staging: wave w, instr i covers slots [w*256 + i*64, +64); slot = r*8 + s,
    // global chunk g = s ^ (r&7). slot0 -> r0 = slot0>>3 (r&7 invariant under +64i).
    const int slot0 = w * 256 + lane;
    const int r0 = slot0 >> 3, s0 = slot0 & 7;
    const int g0 = s0 ^ (r0 & 7);
    const short* gAb = embb + (size_t)(i0 + r0) * DE + g0 * 8;
    const short* gBb = embb + (size_t)(j0 + r0) * DE + g0 * 8;

    auto stage = [&](int ko) {
#pragma unroll
        for (int i = 0; i < 4; ++i) {
            ld_g2l16(gAb + (size_t)(8 * i) * DE + ko * 64, &As[(size_t)(slot0 + 64 * i) * 8]);
            ld_g2l16(gBb + (size_t)(8 * i) * DE + ko * 64, &Bs[(size_t)(slot0 + 64 * i) * 8]);
        }
    };

    f32x4 acc[4][4];
#pragma unroll
    for (int mi = 0; mi < 4; ++mi)
#pragma unroll
        for (int ni = 0; ni < 4; ++ni) acc[mi][ni] = (f32x4){0.f, 0.f, 0.f, 0.f};

    stage(0);
    for (int ko = 0; ko < 16; ++ko) {
        __syncthreads();              // staging visible
#pragma unroll
        for (int k = 0; k < 2; ++k) {
            const int sA = ((q + 4 * k) ^ (l15 & 7)) * 8;
            bf16x8 af[4], bfr[4];
#pragma unroll
            for (int mi = 0; mi < 4; ++mi)
                af[mi] = *(const bf16x8*)&As[(wm * 64 + mi * 16 + l15) * 64 + sA];
#pragma unroll
            for (int ni = 0; ni < 4; ++ni)
                bfr[ni] = *(const bf16x8*)&Bs[(wn * 64 + ni * 16 + l15) * 64 + sA];
#pragma unroll
            for (int mi = 0; mi < 4; ++mi)
#pragma unroll
                for (int ni = 0; ni < 4; ++ni)
                    acc[mi][ni] = __builtin_amdgcn_mfma_f32_16x16x32_bf16(af[mi], bfr[ni], acc[mi][ni], 0, 0, 0);
        }
        __syncthreads();              // reads done before next staging
        if (ko < 15) stage(ko + 1);
    }

    // ---- epilogue: row mins + col mins, straight to atomics ----
    // Diagonal tile (p==q) double-covers pairs from both sides: harmless for min.
    float sqj[4]; int lbj[4];
#pragma unroll
    for (int ni = 0; ni < 4; ++ni) {
        int cg = j0 + wn * 64 + ni * 16 + l15;
        sqj[ni] = sq[cg]; lbj[ni] = label[cg];
    }
    float cmn[4] = {POSI, POSI, POSI, POSI};
#pragma unroll
    for (int mi = 0; mi < 4; ++mi) {
#pragma unroll
        for (int r = 0; r < 4; ++r) {
            const int rowg = i0 + wm * 64 + mi * 16 + q * 4 + r;
            const float si = sq[rowg];
            const int li = label[rowg];
            float rm = POSI;
#pragma unroll
            for (int ni = 0; ni < 4; ++ni) {
                float d2 = fmaf(-2.0f, acc[mi][ni][r], si + sqj[ni]);
                d2 = fmaxf(d2, 1e-12f);
                float dn = (li == lbj[ni]) ? POSI : d2;
                rm = fminf(rm, dn);
                cmn[ni] = fminf(cmn[ni], dn);
            }
            for (int s = 1; s <= 8; s <<= 1) rm = fminf(rm, __shfl_xor(rm, s));
            if (l15 == 0) atomicMin(&mnA[rowg], __float_as_uint(rm));
        }
    }
#pragma unroll
    for (int ni = 0; ni < 4; ++ni) {
        float c = cmn[ni];
        c = fminf(c, __shfl_xor(c, 16));
        c = fminf(c, __shfl_xor(c, 32));
        if (q == 0) atomicMin(&mnA[j0 + wn * 64 + ni * 16 + l15], __float_as_uint(c));
    }
}

// ---------------- K4: exact per-row positives + alphas + loss (block-reduced) ----------------
// one wave per row; classmates in chunks of 8 (ILP); class list preloaded once per wave
// and broadcast via shfl (removes 16 serial dependent scalar loads per row).
__global__ __launch_bounds__(256) void k_pos(const short* __restrict__ embb,
                                             const float* __restrict__ sq,
                                             const float* __restrict__ clot,
                                             const int* __restrict__ label,
                                             const int* __restrict__ cnt,
                                             const int* __restrict__ clsOff,
                                             const int* __restrict__ clsList,
                                             const unsigned* __restrict__ mnA,
                                             float* __restrict__ out) {
    int wid = threadIdx.x >> 6, lane = threadIdx.x & 63;
    int row = blockIdx.x * 4 + wid;
    int lb = label[row];
    int cc = cnt[lb], off = clsOff[lb];
    float sqiv = sq[row];

    int listv = row;
    if (lane < cc && lane < 64) listv = clsList[off + lane];

    const bf16x8* rp = (const bf16x8*)(embb + (size_t)row * DE + lane * 16);
    bf16x8 ra = rp[0], rb = rp[1];
    float rf[16];
#pragma unroll
    for (int u = 0; u < 8; ++u) { rf[u] = b2f(ra[u]); rf[8 + u] = b2f(rb[u]); }

    float v1 = NEGI, v2 = NEGI;
    int i1 = 0, i2 = 0;
    for (int m0 = 0; m0 < cc; m0 += 8) {
        float sv[8], sqj[8]; int jv[8];
#pragma unroll
        for (int u = 0; u < 8; ++u) {
            int mm = m0 + u;
            int j = row;
            if (mm < cc) j = (mm < 64) ? __shfl(listv, mm) : clsList[off + mm];
            jv[u] = j;
            sqj[u] = sq[j];
            const bf16x8* jp = (const bf16x8*)(embb + (size_t)j * DE + lane * 16);
            bf16x8 ja = jp[0], jb = jp[1];
            float s = 0.f;
#pragma unroll
            for (int u2 = 0; u2 < 8; ++u2) s = fmaf(rf[u2], b2f(ja[u2]), s);
#pragma unroll
            for (int u2 = 0; u2 < 8; ++u2) s = fmaf(rf[8 + u2], b2f(jb[u2]), s);
            sv[u] = s;
        }
#pragma unroll
        for (int u = 0; u < 8; ++u)
            for (int mm = 1; mm < 64; mm <<= 1) sv[u] += __shfl_xor(sv[u], mm);
#pragma unroll
        for (int u = 0; u < 8; ++u) {
            int mm = m0 + u;
            if (mm < cc) {
                int j = jv[u];
                float d2 = (j == row) ? 1e-12f
                                      : fmaxf(fmaf(-2.0f, sv[u], sqiv + sqj[u]), 1e-12f);
                bool t1 = (d2 > v1) || (d2 == v1 && j < i1);
                bool t2 = (d2 > v2) || (d2 == v2 && j < i2);
                v2 = t1 ? v1 : (t2 ? d2 : v2);
                i2 = t1 ? i1 : (t2 ? j : i2);
                v1 = t1 ? d2 : v1;
                i1 = t1 ? j : i1;
            }
        }
    }

    float dap1 = sqrtf(v1);
    int j1 = i1;
    float dap2; int j2;
    if (cc >= 2) {
        dap2 = sqrtf(v2);
        j2 = i2;
    } else {
        // singleton class (expected never): ref falls back to max-dist negative - BIG
        float kv = NEGI; int ki = 0;
        const short* rrow = embb + (size_t)row * DE;
        for (int c = lane; c < NR; c += 64) {
            if (label[c] == lb) continue;
            const short* crow = embb + (size_t)c * DE;
            float s = 0.f;
            for (int u = 0; u < DE; ++u) s = fmaf(b2f(rrow[u]), b2f(crow[u]), s);
            float d2c = fmaxf(fmaf(-2.0f, s, sqiv + sq[c]), 1e-12f);
            bool tk = (d2c > kv) || (d2c == kv && c < ki);
            kv = tk ? d2c : kv; ki = tk ? c : ki;
        }
        for (int mm = 1; mm < 64; mm <<= 1) {
            float ov = __shfl_xor(kv, mm); int oi = __shfl_xor(ki, mm);
            bool tk = (ov > kv) || (ov == kv && oi < ki);
            kv = tk ? ov : kv; ki = tk ? oi : ki;
        }
        dap2 = sqrtf(kv) - BIGF;
        j2 = ki;
    }

    // alpha dots + norms over clot
    const float4* c4 = (const float4*)clot;
    float s1 = 0.f, s2 = 0.f, n0 = 0.f, n1 = 0.f, n2 = 0.f;
    for (int u = lane; u < DC / 4; u += 64) {
        float4 a = c4[(size_t)row * (DC / 4) + u];
        float4 b1 = c4[(size_t)j1 * (DC / 4) + u];
        float4 b2 = c4[(size_t)j2 * (DC / 4) + u];
        s1 += a.x * b1.x + a.y * b1.y + a.z * b1.z + a.w * b1.w;
        s2 += a.x * b2.x + a.y * b2.y + a.z * b2.z + a.w * b2.w;
        n0 += a.x * a.x + a.y * a.y + a.z * a.z + a.w * a.w;
        n1 += b1.x * b1.x + b1.y * b1.y + b1.z * b1.z + b1.w * b1.w;
        n2 += b2.x * b2.x + b2.y * b2.y + b2.z * b2.z + b2.w * b2.w;
    }
    for (int mm = 1; mm < 64; mm <<= 1) {
        s1 += __shfl_xor(s1, mm); s2 += __shfl_xor(s2, mm);
        n0 += __shfl_xor(n0, mm); n1 += __shfl_xor(n1, mm); n2 += __shfl_xor(n2, mm);
    }

    __shared__ float sLoss[4], sPrec[4];
    if (lane == 0) {
        float al1 = s1 / (sqrtf(n0) * sqrtf(n1));
        float al2 = s2 / (sqrtf(n0) * sqrtf(n2));
        float dan = sqrtf(__uint_as_float(mnA[row]));
        float y = (al1 < al2) ? -1.f : 1.f;
        float ym = (al1 == al2) ? 0.f : 1.f;
        float x1 = dap2 * ym;
        float x2 = dap1 * ym + MARG * (al1 - al2 - y);
        float l11 = fmaxf(0.f, -y * (x1 - x2) + MARG);
        float ap1m = dap1 + MARG * (al1 - 1.f);
        float l13 = fmaxf(0.f, -(dan - ap1m) + MARG);
        sLoss[wid] = (0.1f * l11 + l13) * (1.0f / (float)NR);
        sPrec[wid] = ((dan > ap1m) ? 1.f : 0.f) * (1.0f / (float)NR);
    }
    __syncthreads();
    if (threadIdx.x == 0) {
        atomicAdd(&out[0], sLoss[0] + sLoss[1] + sLoss[2] + sLoss[3]);
        atomicAdd(&out[1], sPrec[0] + sPrec[1] + sPrec[2] + sPrec[3]);
    }
}

extern "C" void kernel_launch(void* const* d_in, const int* in_sizes, int n_in,
                              void* d_out, int out_size, void* d_ws, size_t ws_size,
                              hipStream_t stream) {
    const float* emb = (const float*)d_in[0];
    const int* label = (const int*)d_in[1];
    const float* clot = (const float*)d_in[2];
    float* out = (float*)d_out;

    char* ws = (char*)d_ws;
    size_t off = 0;
    auto alloc = [&](size_t bytes) -> char* {
        char* p = ws + off;
        off = (off + bytes + 255) & ~(size_t)255;
        return p;
    };
    short*    embb = (short*)alloc((size_t)NR * DE * 2);
    float*    sq   = (float*)alloc(NR * 4);
    int*      cnt  = (int*)alloc(512 * 4);
    int*      cOff = (int*)alloc(512 * 4);
    int*      list = (int*)alloc(NR * 4);
    unsigned* mnA  = (unsigned*)alloc((size_t)NR * 4);

    k_prep_emb<<<dim3(NR), dim3(256), 0, stream>>>(emb, embb, sq, mnA, out);
    k_hist<<<dim3(1), dim3(512), 0, stream>>>(label, cnt, cOff, list);
    k_main<<<dim3(2080), dim3(256), 0, stream>>>(embb, sq, label, mnA);
    k_pos<<<dim3(NR / 4), dim3(256), 0, stream>>>(embb, sq, clot, label, cnt, cOff, list,
                                                  mnA, out);
}